// Round 8
// baseline (120.814 us; speedup 1.0000x reference)
//
#include <hip/hip_runtime.h>

typedef __attribute__((ext_vector_type(8))) short bf16x8;
typedef __attribute__((ext_vector_type(4))) float f32x4;

__device__ inline unsigned short f2bf(float f) {
  union { float f; unsigned u; } v; v.f = f;
  unsigned r = v.u + 0x7FFFu + ((v.u >> 16) & 1u);   // round-to-nearest-even
  return (unsigned short)(r >> 16);
}

// One wave per row of 512 f32: normalize to unit L2 norm, emit bf16 bits.
// Rows [0,8192) = x -> xb ; rows [8192, 12288) = weight -> wb.
__global__ __launch_bounds__(256) void normalize_both(
    const float* __restrict__ x, const float* __restrict__ wgt,
    unsigned short* __restrict__ xb, unsigned short* __restrict__ wb) {
  const int w = threadIdx.x >> 6, lane = threadIdx.x & 63;
  const int row = blockIdx.x * 4 + w;
  const float* src;
  unsigned short* dst;
  if (row < 8192) { src = x + (size_t)row * 512;           dst = xb + (size_t)row * 512; }
  else            { src = wgt + (size_t)(row - 8192) * 512; dst = wb + (size_t)(row - 8192) * 512; }
  const float* p = src + lane * 8;
  float4 a = *reinterpret_cast<const float4*>(p);
  float4 b = *reinterpret_cast<const float4*>(p + 4);
  float ss = a.x*a.x + a.y*a.y + a.z*a.z + a.w*a.w
           + b.x*b.x + b.y*b.y + b.z*b.z + b.w*b.w;
  #pragma unroll
  for (int off = 32; off; off >>= 1) ss += __shfl_xor(ss, off);
  const float inv = 1.0f / fmaxf(sqrtf(ss), 1e-12f);
  unsigned short o[8];
  o[0]=f2bf(a.x*inv); o[1]=f2bf(a.y*inv); o[2]=f2bf(a.z*inv); o[3]=f2bf(a.w*inv);
  o[4]=f2bf(b.x*inv); o[5]=f2bf(b.y*inv); o[6]=f2bf(b.z*inv); o[7]=f2bf(b.w*inv);
  *reinterpret_cast<uint4*>(dst + lane * 8) = *reinterpret_cast<uint4*>(o);
}

// logits[8192,4096] = (1+2l)*(Xn.WnT) - 2l, f16 out.
// 256x256 tile, 8 waves (2Mx4N), K = 16 slots of BK=32.
// R6 cadence (single tile-close barrier, counted vmcnt) upgraded to
// 4 LDS slots / prefetch depth 3 (tile-close wait vmcnt(8), tail 8->4->0).
// SWAPPED-OPERAND MFMA: acc = mfma(W_frag, X_frag) puts reg-index along
// output COLS (col = kg*4+r, row = lrow) -> packed dwordx2 epilogue stores.
// Both-sides XOR swizzle (rule #21) keeps ds_read ~2-way conflict-free.
#define BM 256
#define BN 256
#define BK 32

#define STAGE_A(slot_, ko_, j_)                                                   \
  do {                                                                            \
    const int c_ = wid * 2 + (j_);                                                \
    const unsigned short* s_ = Xb + (size_t)(bm0 + c_ * 16 + srow) * 512 + (ko_) + sskel; \
    __builtin_amdgcn_global_load_lds(                                             \
        (const __attribute__((address_space(1))) void*)s_,                        \
        (__attribute__((address_space(3))) void*)&As[slot_][c_ * 512], 16, 0, 0); \
  } while (0)
#define STAGE_B(slot_, ko_, j_)                                                   \
  do {                                                                            \
    const int c_ = wid * 2 + (j_);                                                \
    const unsigned short* s_ = Wb + (size_t)(bn0 + c_ * 16 + srow) * 512 + (ko_) + sskel; \
    __builtin_amdgcn_global_load_lds(                                             \
        (const __attribute__((address_space(1))) void*)s_,                        \
        (__attribute__((address_space(3))) void*)&Bs[slot_][c_ * 512], 16, 0, 0); \
  } while (0)

__global__ __launch_bounds__(512, 2) void gemm_logits_f16(
    const unsigned short* __restrict__ Xb, const unsigned short* __restrict__ Wb,
    const float* __restrict__ lambd, unsigned short* __restrict__ out16) {
  __shared__ unsigned short As[4][BM * BK];   // 4 x 16 KiB
  __shared__ unsigned short Bs[4][BN * BK];   // 4 x 16 KiB  (total 128 KiB)
  const int tid = threadIdx.x, lane = tid & 63, wid = tid >> 6;  // 8 waves
  const int wm = wid >> 2, wn = wid & 3;          // 2x4 wave grid, 128x64 each
  const int lrow = lane & 15, kg = lane >> 4;

  // bijective XCD swizzle: 512 blocks, 64 per XCD chunk
  const int id = (int)blockIdx.x;
  const int swz = (id & 7) * 64 + (id >> 3);
  const int bx = swz & 15;                 // 4096/256 = 16 col tiles
  const int by = swz >> 4;                 // 8192/256 = 32 row tiles
  const int bm0 = by * BM, bn0 = bx * BN;

  // staging: chunk c = 16 rows x 64 B; lane l -> row c*16 + l/4, landing at
  // LDS byte c*1024 + l*16. Source k-quad swizzled: slot kq holds logical
  // kq ^ ((row>>1)&3); reader applies the same XOR.
  const int srow  = lane >> 2;
  const int sskel = ((lane & 3) ^ ((lane >> 3) & 3)) * 8;

  const int rswz = (lrow >> 1) & 3;
  const int kA = (kg ^ rswz) * 8;     // physical k-quad elem offset for ds_read

  f32x4 acc[8][4];                    // [row-frag fr][col-frag fc]
  #pragma unroll
  for (int m = 0; m < 8; ++m)
    #pragma unroll
    for (int n = 0; n < 4; ++n) { f32x4 z = {0.f,0.f,0.f,0.f}; acc[m][n] = z; }

  // prologue: stage groups G0,G1,G2 (tiles 0,1,2), 4 loads each, FIFO order
  STAGE_A(0, 0, 0);  STAGE_A(0, 0, 1);  STAGE_B(0, 0, 0);  STAGE_B(0, 0, 1);
  STAGE_A(1, 32, 0); STAGE_A(1, 32, 1); STAGE_B(1, 32, 0); STAGE_B(1, 32, 1);
  STAGE_A(2, 64, 0); STAGE_A(2, 64, 1); STAGE_B(2, 64, 0); STAGE_B(2, 64, 1);
  asm volatile("s_waitcnt vmcnt(8)" ::: "memory");   // G0 landed (G1,G2 in flight)
  __builtin_amdgcn_s_barrier();
  __builtin_amdgcn_sched_barrier(0);

  #pragma unroll
  for (int t = 0; t < 16; ++t) {
    const int cur = t & 3, nx3 = (t + 3) & 3;
    // ---- Phase A: stage A-chunks of G_{t+3}; MFMA row-frags 0-3 ----
    if (t + 3 < 16) { STAGE_A(nx3, (t + 3) * BK, 0); STAGE_A(nx3, (t + 3) * BK, 1); }
    bf16x8 af0[4], bfr[4];
    #pragma unroll
    for (int fr = 0; fr < 4; ++fr)
      af0[fr] = *reinterpret_cast<const bf16x8*>(
          &As[cur][(wm * 128 + fr * 16 + lrow) * BK + kA]);
    #pragma unroll
    for (int fc = 0; fc < 4; ++fc)
      bfr[fc] = *reinterpret_cast<const bf16x8*>(
          &Bs[cur][(wn * 64 + fc * 16 + lrow) * BK + kA]);
    asm volatile("s_waitcnt lgkmcnt(0)" ::: "memory");
    __builtin_amdgcn_sched_barrier(0);
    __builtin_amdgcn_s_setprio(1);
    #pragma unroll
    for (int fr = 0; fr < 4; ++fr)
      #pragma unroll
      for (int fc = 0; fc < 4; ++fc)
        acc[fr][fc] = __builtin_amdgcn_mfma_f32_16x16x32_bf16(
            bfr[fc], af0[fr], acc[fr][fc], 0, 0, 0);   // swapped: W first
    __builtin_amdgcn_s_setprio(0);
    __builtin_amdgcn_sched_barrier(0);
    // ---- Phase B: stage B-chunks of G_{t+3}; MFMA row-frags 4-7 ----
    if (t + 3 < 16) { STAGE_B(nx3, (t + 3) * BK, 0); STAGE_B(nx3, (t + 3) * BK, 1); }
    bf16x8 af1[4];
    #pragma unroll
    for (int fr = 0; fr < 4; ++fr)
      af1[fr] = *reinterpret_cast<const bf16x8*>(
          &As[cur][(wm * 128 + 64 + fr * 16 + lrow) * BK + kA]);
    asm volatile("s_waitcnt lgkmcnt(0)" ::: "memory");
    __builtin_amdgcn_sched_barrier(0);
    __builtin_amdgcn_s_setprio(1);
    #pragma unroll
    for (int fr = 0; fr < 4; ++fr)
      #pragma unroll
      for (int fc = 0; fc < 4; ++fc)
        acc[fr + 4][fc] = __builtin_amdgcn_mfma_f32_16x16x32_bf16(
            bfr[fc], af1[fr], acc[fr + 4][fc], 0, 0, 0);
    __builtin_amdgcn_s_setprio(0);
    __builtin_amdgcn_sched_barrier(0);
    // ---- tile close: counted wait for G_{t+1}; G_{t+2},G_{t+3} stay in flight
    if (t < 15) {
      if (t <= 12)      { asm volatile("s_waitcnt vmcnt(8)" ::: "memory"); }
      else if (t == 13) { asm volatile("s_waitcnt vmcnt(4)" ::: "memory"); }
      else              { asm volatile("s_waitcnt vmcnt(0)" ::: "memory"); }
      __builtin_amdgcn_s_barrier();
      __builtin_amdgcn_sched_barrier(0);
    }
  }

  // Epilogue: lane holds out[row = frbase+lrow][col = fcbase + kg*4 + r],
  // r=0..3 consecutive cols -> pack 4 f16 (RNE) -> one dwordx2 store.
  const float lam = lambd[0];
  const float sa_ = 1.0f + 2.0f * lam, sb_ = 2.0f * lam;
  #pragma unroll
  for (int fr = 0; fr < 8; ++fr) {
    const int gr = bm0 + wm * 128 + fr * 16 + lrow;
    #pragma unroll
    for (int fc = 0; fc < 4; ++fc) {
      const int gc = bn0 + wn * 64 + fc * 16 + kg * 4;
      union { _Float16 h[2]; unsigned u; } p0, p1;
      p0.h[0] = (_Float16)(sa_ * acc[fr][fc][0] - sb_);
      p0.h[1] = (_Float16)(sa_ * acc[fr][fc][1] - sb_);
      p1.h[0] = (_Float16)(sa_ * acc[fr][fc][2] - sb_);
      p1.h[1] = (_Float16)(sa_ * acc[fr][fc][3] - sb_);
      uint2 pk; pk.x = p0.u; pk.y = p1.u;
      *reinterpret_cast<uint2*>(&out16[(size_t)gr * 4096 + gc]) = pk;
    }
  }
}

// Sparsemax per row of 4096: f16 logits in, f32 out. Michelot from full-set
// start; double-buffered reduce scratch -> ONE barrier per iteration.
__global__ __launch_bounds__(256) void sparsemax_f16(
    const unsigned short* __restrict__ zin, float* __restrict__ out) {
  const int tid = threadIdx.x;
  const unsigned short* zr = zin + (size_t)blockIdx.x * 4096;
  float* orow = out + (size_t)blockIdx.x * 4096;

  float v[16];
  #pragma unroll
  for (int b = 0; b < 2; ++b) {
    uint4 pk = *reinterpret_cast<const uint4*>(&zr[b * 2048 + tid * 8]);
    const unsigned short* ph = reinterpret_cast<const unsigned short*>(&pk);
    #pragma unroll
    for (int j = 0; j < 8; ++j) {
      union { unsigned short u; _Float16 h; } cv; cv.u = ph[j];
      v[b * 8 + j] = (float)cv.h;
    }
  }

  __shared__ float sred[2][4];
  __shared__ int   cred[2][4];
  const int lane = tid & 63, w = tid >> 6;

  // full-set start: tau0 = (sum - 1)/4096
  float ls = 0.f;
  #pragma unroll
  for (int j = 0; j < 16; ++j) ls += v[j];
  #pragma unroll
  for (int off = 32; off; off >>= 1) ls += __shfl_xor(ls, off);
  if (lane == 0) sred[0][w] = ls;
  __syncthreads();
  float tau = (sred[0][0] + sred[0][1] + sred[0][2] + sred[0][3] - 1.0f)
              * (1.0f / 4096.0f);
  int prevC = 4096;

  for (int it = 0; it < 32; ++it) {
    const int pw = 1 - (it & 1);         // alternate scratch slot (WAR-safe, 1 barrier)
    float s = 0.f; int c = 0;
    #pragma unroll
    for (int j = 0; j < 16; ++j) { if (v[j] > tau) { s += v[j]; ++c; } }
    #pragma unroll
    for (int off = 32; off; off >>= 1) { s += __shfl_xor(s, off); c += __shfl_xor(c, off); }
    if (lane == 0) { sred[pw][w] = s; cred[pw][w] = c; }
    __syncthreads();
    const float S = sred[pw][0] + sred[pw][1] + sred[pw][2] + sred[pw][3];
    const int   C = cred[pw][0] + cred[pw][1] + cred[pw][2] + cred[pw][3];
    tau = (S - 1.0f) / (float)C;      // nested supports: equal count => converged
    if (C == prevC) break;
    prevC = C;
  }

  #pragma unroll
  for (int b = 0; b < 2; ++b) {
    float4 t0, t1;
    t0.x = fmaxf(v[b*8+0] - tau, 0.f);
    t0.y = fmaxf(v[b*8+1] - tau, 0.f);
    t0.z = fmaxf(v[b*8+2] - tau, 0.f);
    t0.w = fmaxf(v[b*8+3] - tau, 0.f);
    t1.x = fmaxf(v[b*8+4] - tau, 0.f);
    t1.y = fmaxf(v[b*8+5] - tau, 0.f);
    t1.z = fmaxf(v[b*8+6] - tau, 0.f);
    t1.w = fmaxf(v[b*8+7] - tau, 0.f);
    *reinterpret_cast<float4*>(&orow[b * 2048 + tid * 8])     = t0;
    *reinterpret_cast<float4*>(&orow[b * 2048 + tid * 8 + 4]) = t1;
  }
}

extern "C" void kernel_launch(void* const* d_in, const int* in_sizes, int n_in,
                              void* d_out, int out_size, void* d_ws, size_t ws_size,
                              hipStream_t stream) {
  const float* x     = (const float*)d_in[0];   // [8192, 512]
  const float* wgt   = (const float*)d_in[1];   // [4096, 512]
  const float* lambd = (const float*)d_in[2];   // [1]
  float* out = (float*)d_out;                   // [8192, 4096] f32

  unsigned short* xb  = (unsigned short*)d_ws;            // 8192*512 bf16 (8 MB)
  unsigned short* wb  = xb + (size_t)8192 * 512;          // 4096*512 bf16 (4 MB)
  unsigned short* z16 = wb + (size_t)4096 * 512;          // 8192*4096 f16 (64 MB)

  normalize_both<<<(8192 + 4096) / 4, 256, 0, stream>>>(x, wgt, xb, wb);

  gemm_logits_f16<<<512, 512, 0, stream>>>(xb, wb, lambd, z16);

  sparsemax_f16<<<8192, 256, 0, stream>>>(z16, out);
}

// Round 9
// 94.830 us; speedup vs baseline: 1.2740x; 1.2740x over previous
//
#include <hip/hip_runtime.h>

typedef __attribute__((ext_vector_type(8))) short bf16x8;
typedef __attribute__((ext_vector_type(4))) float f32x4;

__device__ inline unsigned short f2bf(float f) {
  union { float f; unsigned u; } v; v.f = f;
  unsigned r = v.u + 0x7FFFu + ((v.u >> 16) & 1u);   // round-to-nearest-even
  return (unsigned short)(r >> 16);
}

// One wave per row of 512 f32: normalize to unit L2 norm, emit bf16 bits.
// Rows [0,8192) = x -> xb ; rows [8192, 12288) = weight -> wb.
__global__ __launch_bounds__(256) void normalize_both(
    const float* __restrict__ x, const float* __restrict__ wgt,
    unsigned short* __restrict__ xb, unsigned short* __restrict__ wb) {
  const int w = threadIdx.x >> 6, lane = threadIdx.x & 63;
  const int row = blockIdx.x * 4 + w;
  const float* src;
  unsigned short* dst;
  if (row < 8192) { src = x + (size_t)row * 512;           dst = xb + (size_t)row * 512; }
  else            { src = wgt + (size_t)(row - 8192) * 512; dst = wb + (size_t)(row - 8192) * 512; }
  const float* p = src + lane * 8;
  float4 a = *reinterpret_cast<const float4*>(p);
  float4 b = *reinterpret_cast<const float4*>(p + 4);
  float ss = a.x*a.x + a.y*a.y + a.z*a.z + a.w*a.w
           + b.x*b.x + b.y*b.y + b.z*b.z + b.w*b.w;
  #pragma unroll
  for (int off = 32; off; off >>= 1) ss += __shfl_xor(ss, off);
  const float inv = 1.0f / fmaxf(sqrtf(ss), 1e-12f);
  unsigned short o[8];
  o[0]=f2bf(a.x*inv); o[1]=f2bf(a.y*inv); o[2]=f2bf(a.z*inv); o[3]=f2bf(a.w*inv);
  o[4]=f2bf(b.x*inv); o[5]=f2bf(b.y*inv); o[6]=f2bf(b.z*inv); o[7]=f2bf(b.w*inv);
  *reinterpret_cast<uint4*>(dst + lane * 8) = *reinterpret_cast<uint4*>(o);
}

// logits[8192,4096] = (1+2l)*(Xn.WnT) - 2l, f16 out.  ===== EXACT R6 GEMM =====
// 256x256 tile, BK=32, 8 waves (2Mx4N), TRIPLE-buffered LDS (96 KiB),
// counted-vmcnt pipeline (prefetch distance 2, boundary wait vmcnt(4)),
// both-sides XOR swizzle (rule #21): linear gload_lds dest, source k-quad
// pre-swizzled by kq ^= (row>>1)&3, ds_read applies the same XOR.
#define BM 256
#define BN 256
#define BK 32

#define STAGE_A(slot_, ko_, j_)                                                   \
  do {                                                                            \
    const int c_ = wid * 2 + (j_);                                                \
    const unsigned short* s_ = Xb + (size_t)(bm0 + c_ * 16 + srow) * 512 + (ko_) + sskel; \
    __builtin_amdgcn_global_load_lds(                                             \
        (const __attribute__((address_space(1))) void*)s_,                        \
        (__attribute__((address_space(3))) void*)&As[slot_][c_ * 512], 16, 0, 0); \
  } while (0)
#define STAGE_B(slot_, ko_, j_)                                                   \
  do {                                                                            \
    const int c_ = wid * 2 + (j_);                                                \
    const unsigned short* s_ = Wb + (size_t)(bn0 + c_ * 16 + srow) * 512 + (ko_) + sskel; \
    __builtin_amdgcn_global_load_lds(                                             \
        (const __attribute__((address_space(1))) void*)s_,                        \
        (__attribute__((address_space(3))) void*)&Bs[slot_][c_ * 512], 16, 0, 0); \
  } while (0)

__global__ __launch_bounds__(512, 2) void gemm_logits_f16(
    const unsigned short* __restrict__ Xb, const unsigned short* __restrict__ Wb,
    const float* __restrict__ lambd, unsigned short* __restrict__ out16) {
  __shared__ unsigned short As[3][BM * BK];   // 3 x 16 KiB
  __shared__ unsigned short Bs[3][BN * BK];   // 3 x 16 KiB
  const int tid = threadIdx.x, lane = tid & 63, wid = tid >> 6;  // 8 waves
  const int wm = wid >> 2, wn = wid & 3;          // 2x4 wave grid, 128x64 each
  const int lrow = lane & 15, kg = lane >> 4;

  // bijective XCD swizzle: 512 blocks, 64 per XCD chunk
  const int id = (int)blockIdx.x;
  const int swz = (id & 7) * 64 + (id >> 3);
  const int bx = swz & 15;                 // 4096/256 = 16 col tiles
  const int by = swz >> 4;                 // 8192/256 = 32 row tiles
  const int bm0 = by * BM, bn0 = bx * BN;

  const int srow  = lane >> 2;
  const int sskel = ((lane & 3) ^ ((lane >> 3) & 3)) * 8;   // swizzled k-elem offset

  const int rswz = (lrow >> 1) & 3;
  const int kA = (kg ^ rswz) * 8;     // physical k-quad elem offset for ds_read

  f32x4 acc[8][4];
  #pragma unroll
  for (int m = 0; m < 8; ++m)
    #pragma unroll
    for (int n = 0; n < 4; ++n) { f32x4 z = {0.f,0.f,0.f,0.f}; acc[m][n] = z; }

  // prologue: stage tiles 0 and 1
  STAGE_A(0, 0, 0); STAGE_A(0, 0, 1); STAGE_B(0, 0, 0); STAGE_B(0, 0, 1);
  STAGE_A(1, BK, 0); STAGE_A(1, BK, 1); STAGE_B(1, BK, 0); STAGE_B(1, BK, 1);
  asm volatile("s_waitcnt vmcnt(4)" ::: "memory");   // tile 0's 4 (oldest) landed
  __builtin_amdgcn_s_barrier();
  __builtin_amdgcn_sched_barrier(0);

  #pragma unroll
  for (int t = 0; t < 16; ++t) {
    const int cur = t % 3, nx2 = (t + 2) % 3;
    // ---- Phase A: stage A-chunks of t+2; compute mf0-3 x nf0-3 ----
    if (t + 2 < 16) { STAGE_A(nx2, (t + 2) * BK, 0); STAGE_A(nx2, (t + 2) * BK, 1); }
    bf16x8 af0[4], bfr[4];
    #pragma unroll
    for (int mf = 0; mf < 4; ++mf)
      af0[mf] = *reinterpret_cast<const bf16x8*>(
          &As[cur][(wm * 128 + mf * 16 + lrow) * BK + kA]);
    #pragma unroll
    for (int nf = 0; nf < 4; ++nf)
      bfr[nf] = *reinterpret_cast<const bf16x8*>(
          &Bs[cur][(wn * 64 + nf * 16 + lrow) * BK + kA]);
    asm volatile("s_waitcnt lgkmcnt(0)" ::: "memory");
    __builtin_amdgcn_sched_barrier(0);
    __builtin_amdgcn_s_setprio(1);
    #pragma unroll
    for (int mf = 0; mf < 4; ++mf)
      #pragma unroll
      for (int nf = 0; nf < 4; ++nf)
        acc[mf][nf] = __builtin_amdgcn_mfma_f32_16x16x32_bf16(
            af0[mf], bfr[nf], acc[mf][nf], 0, 0, 0);
    __builtin_amdgcn_s_setprio(0);
    __builtin_amdgcn_sched_barrier(0);
    // ---- Phase B: stage B-chunks of t+2; compute mf4-7 x nf0-3 ----
    if (t + 2 < 16) { STAGE_B(nx2, (t + 2) * BK, 0); STAGE_B(nx2, (t + 2) * BK, 1); }
    bf16x8 af1[4];
    #pragma unroll
    for (int mf = 0; mf < 4; ++mf)
      af1[mf] = *reinterpret_cast<const bf16x8*>(
          &As[cur][(wm * 128 + 64 + mf * 16 + lrow) * BK + kA]);
    asm volatile("s_waitcnt lgkmcnt(0)" ::: "memory");
    __builtin_amdgcn_sched_barrier(0);
    __builtin_amdgcn_s_setprio(1);
    #pragma unroll
    for (int mf = 0; mf < 4; ++mf)
      #pragma unroll
      for (int nf = 0; nf < 4; ++nf)
        acc[mf + 4][nf] = __builtin_amdgcn_mfma_f32_16x16x32_bf16(
            af1[mf], bfr[nf], acc[mf + 4][nf], 0, 0, 0);
    __builtin_amdgcn_s_setprio(0);
    __builtin_amdgcn_sched_barrier(0);
    // ---- tile boundary: ensure tile t+1 resident, keep t+2's loads in flight
    if (t < 15) {
      if (t < 13) { asm volatile("s_waitcnt vmcnt(4)" ::: "memory"); }
      else        { asm volatile("s_waitcnt vmcnt(0)" ::: "memory"); }
      __builtin_amdgcn_s_barrier();
      __builtin_amdgcn_sched_barrier(0);
    }
  }

  const float lam = lambd[0];
  const float sa_ = 1.0f + 2.0f * lam, sb_ = 2.0f * lam;
  #pragma unroll
  for (int mf = 0; mf < 8; ++mf) {
    #pragma unroll
    for (int nf = 0; nf < 4; ++nf) {
      const int gc = bn0 + wn * 64 + nf * 16 + lrow;
      #pragma unroll
      for (int r = 0; r < 4; ++r) {
        const int gr = bm0 + wm * 128 + mf * 16 + kg * 4 + r;  // C/D: col=lane&15, row=(lane>>4)*4+r
        union { _Float16 h; unsigned short u; } cv;
        cv.h = (_Float16)(sa_ * acc[mf][nf][r] - sb_);
        out16[(size_t)gr * 4096 + gc] = cv.u;
      }
    }
  }
}

// Sparsemax per row of 4096: f16 logits in, f32 out.
// ONE WAVE PER ROW: 64 elems/lane in registers, all reductions via
// __shfl_xor butterflies -> ZERO barriers, zero LDS, no inter-wave coupling.
// Convergence break is wave-uniform (post-butterfly S,C identical per lane).
__global__ __launch_bounds__(256) void sparsemax_wave(
    const unsigned short* __restrict__ zin, float* __restrict__ out) {
  const int lane = threadIdx.x & 63;
  const int row  = ((int)blockIdx.x << 2) + (threadIdx.x >> 6);  // 4 rows/block
  const unsigned short* zr = zin + (size_t)row * 4096;
  float* orow = out + (size_t)row * 4096;

  float v[64];
  #pragma unroll
  for (int c = 0; c < 8; ++c) {
    uint4 pk = *reinterpret_cast<const uint4*>(&zr[c * 512 + lane * 8]);  // 1 KB/instr, coalesced
    const unsigned short* ph = reinterpret_cast<const unsigned short*>(&pk);
    #pragma unroll
    for (int j = 0; j < 8; ++j) {
      union { unsigned short u; _Float16 h; } cv; cv.u = ph[j];
      v[c * 8 + j] = (float)cv.h;
    }
  }

  // full-set start: tau0 = (sum - 1)/4096
  float ls = 0.f;
  #pragma unroll
  for (int j = 0; j < 64; ++j) ls += v[j];
  #pragma unroll
  for (int off = 32; off; off >>= 1) ls += __shfl_xor(ls, off);
  float tau = (ls - 1.0f) * (1.0f / 4096.0f);
  int prevC = 4096;

  for (int it = 0; it < 32; ++it) {
    float s = 0.f; int c = 0;
    #pragma unroll
    for (int j = 0; j < 64; ++j) { if (v[j] > tau) { s += v[j]; ++c; } }
    #pragma unroll
    for (int off = 32; off; off >>= 1) { s += __shfl_xor(s, off); c += __shfl_xor(c, off); }
    tau = (s - 1.0f) / (float)c;      // nested supports: equal count => converged
    if (c == prevC) break;            // wave-uniform branch
    prevC = c;
  }

  #pragma unroll
  for (int c = 0; c < 8; ++c) {
    float4 t0, t1;
    t0.x = fmaxf(v[c*8+0] - tau, 0.f);
    t0.y = fmaxf(v[c*8+1] - tau, 0.f);
    t0.z = fmaxf(v[c*8+2] - tau, 0.f);
    t0.w = fmaxf(v[c*8+3] - tau, 0.f);
    t1.x = fmaxf(v[c*8+4] - tau, 0.f);
    t1.y = fmaxf(v[c*8+5] - tau, 0.f);
    t1.z = fmaxf(v[c*8+6] - tau, 0.f);
    t1.w = fmaxf(v[c*8+7] - tau, 0.f);
    *reinterpret_cast<float4*>(&orow[c * 512 + lane * 8])     = t0;
    *reinterpret_cast<float4*>(&orow[c * 512 + lane * 8 + 4]) = t1;
  }
}

extern "C" void kernel_launch(void* const* d_in, const int* in_sizes, int n_in,
                              void* d_out, int out_size, void* d_ws, size_t ws_size,
                              hipStream_t stream) {
  const float* x     = (const float*)d_in[0];   // [8192, 512]
  const float* wgt   = (const float*)d_in[1];   // [4096, 512]
  const float* lambd = (const float*)d_in[2];   // [1]
  float* out = (float*)d_out;                   // [8192, 4096] f32

  unsigned short* xb  = (unsigned short*)d_ws;            // 8192*512 bf16 (8 MB)
  unsigned short* wb  = xb + (size_t)8192 * 512;          // 4096*512 bf16 (4 MB)
  unsigned short* z16 = wb + (size_t)4096 * 512;          // 8192*4096 f16 (64 MB)

  normalize_both<<<(8192 + 4096) / 4, 256, 0, stream>>>(x, wgt, xb, wb);

  gemm_logits_f16<<<512, 512, 0, stream>>>(xb, wb, lambd, z16);

  sparsemax_wave<<<8192 / 4, 256, 0, stream>>>(z16, out);
}